// Round 3
// baseline (2840.622 us; speedup 1.0000x reference)
//
#include <hip/hip_runtime.h>

#define S 128
#define NEG_INF (-__builtin_huge_valf())
#define MAXB 16

// Static device workspace — eliminates any dependence on d_ws/ws_size.
// Every cell read is written earlier in the same launch => deterministic.
__device__ float g_ssg[MAXB * S * S];   // sibling spans, both orientations
__device__ float g_logZ[MAXB];
__device__ float g_partials[512];

// Mask may arrive as bool bytes (expected) or int32; detect from row 0
// (bool: 127 nonzero bytes of first 128; int32: ~31).
__device__ __forceinline__ bool mask_is_bytes(const unsigned char* mask) {
  int c = 0;
  for (int i = 0; i < S; ++i) c += (mask[i] != 0);
  return c >= 64;
}
__device__ __forceinline__ bool mask_at(const unsigned char* mask, int idx, bool bytes) {
  return bytes ? (mask[idx] != 0) : (((const int*)mask)[idx] != 0);
}

// logsumexp across the 64-lane wave of {v0, v1} per lane (128 candidates),
// with the reference's exact -inf semantics: m = isfinite(max) ? max : 0,
// result = s > 0 ? log(s) + m : -inf.
__device__ __forceinline__ float wave_lse2(float v0, float v1) {
  float m = fmaxf(v0, v1);
#pragma unroll
  for (int off = 32; off; off >>= 1) m = fmaxf(m, __shfl_xor(m, off, 64));
  float mf = isfinite(m) ? m : 0.0f;
  float s = expf(v0 - mf) + expf(v1 - mf);
#pragma unroll
  for (int off = 32; off; off >>= 1) s += __shfl_xor(s, off, 64);
  return (s > 0.0f) ? (logf(s) + mf) : NEG_INF;
}

// One block (1024 threads = 16 waves) per batch element. Literal port of the
// reference scan: per width w, phase 1 computes ir/il/slr (reading widths < w),
// phase 2 computes cl/cr (reading s_i updated at this width).
__global__ __launch_bounds__(1024) void dp_kernel(
    const float* __restrict__ arc,          // [B,S,S] s_arc[b,dep,head]
    const float* __restrict__ sib,          // [B,S,S,S] s_sib[b,dep,head,sib]
    const unsigned char* __restrict__ mask) // [B,S]
{
  __shared__ float si[S][S];
  __shared__ float sc[S][S];
  __shared__ int len_sh;

  const int b = blockIdx.x;
  const int tid = threadIdx.x;
  const int g = tid & 63;
  const int wid = tid >> 6;
  const float* arc_b = arc + (size_t)b * S * S;      // arc_b[dep*S+head]
  const float* SBraw = sib + (size_t)b * S * S * S;  // SBraw[dep][head][sib]
  float* ssg = g_ssg + (size_t)b * S * S;

  if (tid == 0) {
    const bool bytes = mask_is_bytes(mask);
    int l = 0;
    for (int i = 0; i < S; ++i) l += mask_at(mask, b * S + i, bytes) ? 1 : 0;
    len_sh = l;
  }
  for (int i = tid; i < S * S; i += 1024) {
    (&si[0][0])[i] = NEG_INF;
    (&sc[0][0])[i] = NEG_INF;
  }
  __syncthreads();
  if (tid < S) sc[tid][tid] = 0.0f;   // width-0 complete spans
  __syncthreads();
  const int len = min(len_sh, S - 1);
  if (tid == 0) g_logZ[b] = 0.0f;     // len==0 fallback; overwritten at w==len

  for (int w = 1; w < S; ++w) {
    const int nk = S - w;
    // ---- phase 1: type0=ir, type1=il, type2=slr; k in [0, nk) ----
    for (int task = wid; task < 3 * nk; task += 16) {
      const int type = (task < nk) ? 0 : ((task < 2 * nk) ? 1 : 2);
      const int k = task - type * nk;
      const int kw = k + w;
      if (type == 0) {
        // I(k -> kw): j=0 first-dep; j in [1,w) siblings (k>0 only)
        const float* SBr = SBraw + (size_t)(kw * S + k) * S;  // sib[b,dep=kw,head=k,:]
        auto term = [&](int j) -> float {
          if (j >= w) return NEG_INF;
          if (j == 0) return sc[k][k] + sc[kw][k + 1];
          if (k == 0) return NEG_INF;
          return si[k][k + j] + ssg[kw * S + k + j] + SBr[k + j];
        };
        float r = wave_lse2(term(g), term(g + 64));
        if (g == 0) si[k][kw] = r + arc_b[kw * S + k];  // + A[head=k,dep=kw]
      } else if (type == 1) {
        // I(kw -> k): j=w-1 first-dep; j in [0,w-1) siblings
        const float* SBr = SBraw + (size_t)(k * S + kw) * S;  // sib[b,dep=k,head=kw,:]
        auto term = [&](int j) -> float {
          if (j >= w) return NEG_INF;
          if (j == w - 1) return (k == 0) ? 0.0f : (sc[kw][kw] + sc[k][kw - 1]);
          return si[kw][k + j + 1] + ssg[k * S + k + j + 1] + SBr[k + j + 1];
        };
        float r = wave_lse2(term(g), term(g + 64));
        if (g == 0) si[kw][k] = r + arc_b[k * S + kw];  // + A[head=kw,dep=k]
      } else {
        // S(k, kw) = lse_j C(k->k+j) + C(kw->k+j+1)
        auto term = [&](int j) -> float {
          if (j >= w) return NEG_INF;
          return sc[k][k + j] + sc[kw][k + j + 1];
        };
        float r = wave_lse2(term(g), term(g + 64));
        if (g == 0) { ssg[k * S + kw] = r; ssg[kw * S + k] = r; }
      }
    }
    __syncthreads();
    // ---- phase 2: type0=cl, type1=cr; k in [0, nk) ----
    for (int task = wid; task < 2 * nk; task += 16) {
      const int type = (task < nk) ? 0 : 1;
      const int k = task - type * nk;
      const int kw = k + w;
      if (type == 0) {
        // C(kw -> k) = lse_j C(k+j -> k) + I(kw -> k+j)
        auto term = [&](int j) -> float {
          if (j >= w) return NEG_INF;
          return sc[k + j][k] + si[kw][k + j];
        };
        float r = wave_lse2(term(g), term(g + 64));
        if (g == 0) sc[kw][k] = r;
      } else {
        // C(k -> kw) = lse_j I(k -> k+j+1) + C(k+j+1 -> kw)
        auto term = [&](int j) -> float {
          if (j >= w) return NEG_INF;
          return si[k][k + j + 1] + sc[k + j + 1][kw];
        };
        float r = wave_lse2(term(g), term(g + 64));
        if (g == 0) {
          if (k == 0) {
            // single-root kill: C(0->w) survives only at w == len
            if (w == len) { g_logZ[b] = r; sc[0][w] = r; }
            else sc[0][w] = NEG_INF;
          } else {
            sc[k][kw] = r;
          }
        }
      }
    }
    __syncthreads();
  }
}

// Gather score: masked arc scores + positive-sibling scores, count mask.
__global__ __launch_bounds__(256) void score_kernel(
    const float* __restrict__ arc, const float* __restrict__ sib,
    const unsigned char* __restrict__ mask, const int* __restrict__ arcs,
    const int* __restrict__ sibs, int B)
{
  __shared__ bool bytes_sh;
  if (threadIdx.x == 0) bytes_sh = mask_is_bytes(mask);
  __syncthreads();
  const bool bytes = bytes_sh;

  const int total = B * S * S;
  int tid = blockIdx.x * blockDim.x + threadIdx.x;
  float sum = 0.f, cnt = 0.f;
  for (int e = tid; e < total; e += gridDim.x * blockDim.x) {
    int sv = sibs[e];
    if (sv > 0) sum += sib[(size_t)e * S + sv];
    if ((e & (S - 1)) == 0) {           // once per (b,i)
      int bi = e >> 7;
      if (mask_at(mask, bi, bytes)) { sum += arc[(size_t)bi * S + arcs[bi]]; cnt += 1.f; }
    }
  }
  __shared__ float rs[256], rc[256];
  rs[threadIdx.x] = sum; rc[threadIdx.x] = cnt;
  __syncthreads();
  for (int off = 128; off; off >>= 1) {
    if (threadIdx.x < off) {
      rs[threadIdx.x] += rs[threadIdx.x + off];
      rc[threadIdx.x] += rc[threadIdx.x + off];
    }
    __syncthreads();
  }
  if (threadIdx.x == 0) {
    g_partials[blockIdx.x * 2]     = rs[0];
    g_partials[blockIdx.x * 2 + 1] = rc[0];
  }
}

__global__ __launch_bounds__(256) void final_kernel(int B, float* __restrict__ out)
{
  __shared__ float rs[256], rc[256];
  int t = threadIdx.x;
  float v = -g_partials[t * 2];
  float c = g_partials[t * 2 + 1];
  if (t < B) v += g_logZ[t];
  rs[t] = v; rc[t] = c;
  __syncthreads();
  for (int off = 128; off; off >>= 1) {
    if (t < off) { rs[t] += rs[t + off]; rc[t] += rc[t + off]; }
    __syncthreads();
  }
  if (t == 0) out[0] = rs[0] / rc[0];   // (logZ - score) / mask.sum()
}

extern "C" void kernel_launch(void* const* d_in, const int* in_sizes, int n_in,
                              void* d_out, int out_size, void* d_ws, size_t ws_size,
                              hipStream_t stream) {
  const float* s_arc = (const float*)d_in[0];
  const float* s_sib = (const float*)d_in[1];
  const unsigned char* mask = (const unsigned char*)d_in[2];
  const int* arcs = (const int*)d_in[3];
  const int* sibs = (const int*)d_in[4];
  int B = in_sizes[0] / (S * S);
  if (B > MAXB) B = MAXB;

  score_kernel<<<dim3(256), dim3(256), 0, stream>>>(s_arc, s_sib, mask, arcs, sibs, B);
  dp_kernel<<<dim3(B), dim3(1024), 0, stream>>>(s_arc, s_sib, mask);
  final_kernel<<<dim3(1), dim3(256), 0, stream>>>(B, (float*)d_out);
}

// Round 4
// 2529.511 us; speedup vs baseline: 1.1230x; 1.1230x over previous
//
#include <hip/hip_runtime.h>

#define S 128
#define NEGF (-1e30f)
#define MAXB 16
#define MAXT 24   // max phase-1 tasks per wave: ceil(3*127/16)

// Static device workspace (d_ws proved unreliable in rounds 0-2).
__device__ float g_ssg[MAXB * S * S];   // sibling spans, both orientations
__device__ float g_logZ[MAXB];
__device__ float g_partials[512];

// sc is read both row-wise and column-wise: XOR-swizzle the column index so
// column reads (row varies per lane, col fixed) spread across banks.
#define SC(r, c) sc[r][(c) ^ ((r) & 31)]

__device__ __forceinline__ bool mask_at(const unsigned char* mask, int idx, bool bytes) {
  return bytes ? (mask[idx] != 0) : (((const int*)mask)[idx] != 0);
}

// logsumexp across the 64-lane wave of {v0,v1} per lane. Finite sentinel
// -1e30: all-dead rows give ~-1e30+log(128) (still dead); mixed rows get
// exp(-huge)=0 contributions. No inf => no NaN with fast math.
__device__ __forceinline__ float wave_lse2(float v0, float v1) {
  float m = fmaxf(v0, v1);
#pragma unroll
  for (int off = 32; off; off >>= 1) m = fmaxf(m, __shfl_xor(m, off, 64));
  float s = __expf(v0 - m) + __expf(v1 - m);
#pragma unroll
  for (int off = 32; off; off >>= 1) s += __shfl_xor(s, off, 64);
  return __logf(s) + m;
}

// One block (16 waves) per batch element. Per width w: phase 1 = ir/il/slr,
// phase 2 = cl/cr (+ root kill). Global loads for width w+1 (sib rows, ssg)
// are prefetched into register arrays during width w's phase 2, so their
// ~900-cycle latency hides under a full phase + barrier.
__global__ __launch_bounds__(1024) void dp_kernel(
    const float* __restrict__ arc,          // [B,S,S] s_arc[b,dep,head]
    const float* __restrict__ sib,          // [B,S,S,S] s_sib[b,dep,head,sib]
    const unsigned char* __restrict__ mask) // [B,S]
{
  __shared__ float si[S][S];
  __shared__ float sc[S][S];
  __shared__ int len_sh, cnt0_sh;

  const int b = blockIdx.x;
  const int tid = threadIdx.x;
  const int g = tid & 63;
  const int wid = tid >> 6;
  const float* arc_b = arc + (size_t)b * S * S;      // arc_b[dep*S+head]
  const float* SBraw = sib + (size_t)b * S * S * S;  // SBraw[dep][head][sib]
  float* ssg = g_ssg + (size_t)b * S * S;

  if (tid == 0) { len_sh = 0; cnt0_sh = 0; }
  __syncthreads();
  if (tid < S && mask[tid] != 0) atomicAdd(&cnt0_sh, 1);  // byte-interp of row 0
  for (int i = tid; i < S * S; i += 1024) {
    (&si[0][0])[i] = NEGF;
    (&sc[0][0])[i] = NEGF;
  }
  __syncthreads();
  const bool bytes = (cnt0_sh >= 64);  // bool bytes: ~127 nonzero; int32: ~31
  if (tid < S) {
    SC(tid, tid) = 0.0f;               // width-0 complete spans
    if (mask_at(mask, b * S + tid, bytes)) atomicAdd(&len_sh, 1);
  }
  __syncthreads();
  const int len = min(len_sh, S - 1);
  if (tid == 0) g_logZ[b] = 0.0f;      // len==0 fallback

  // Prefetch slots: slot t <-> phase-1 task (wid + 16*t). For w>64 there are
  // <12 tasks/wave, so slots 12..23 hold the j=g+64 values (hi overlay).
  float pf_sib[MAXT], pf_ssg[MAXT];

  for (int w = 1; w < S; ++w) {
    const int nk = S - w;
    const int T1 = 3 * nk;

    // ---- phase 1: type0=ir, type1=il, type2=slr (unrolled for pf regs) ----
#pragma unroll
    for (int t = 0; t < MAXT; ++t) {
      const int task = wid + 16 * t;
      if (task < T1) {
        const int type = (task < nk) ? 0 : ((task < 2 * nk) ? 1 : 2);
        const int k = task - type * nk;
        const int kw = k + w;
        float v0 = NEGF, v1 = NEGF;
        if (type == 0) {
          // I(k -> kw): j=0 base; j in [1,w) siblings (k>=1 only)
          if (g == 0) v0 = SC(k, k) + SC(kw, k + 1);
          else if (g < w && k >= 1) v0 = si[k][k + g] + pf_ssg[t] + pf_sib[t];
          if (w > 64 && k >= 1) {
            int j = g + 64;
            if (j < w) v1 = si[k][k + j] + pf_ssg[12 + t] + pf_sib[12 + t];
          }
          float r = wave_lse2(v0, v1);
          if (g == 0) si[k][kw] = r + arc_b[kw * S + k];
        } else if (type == 1) {
          // I(kw -> k): j=w-1 base; j in [0,w-1) siblings (k>=1 only)
          if (g == w - 1) v0 = (k == 0) ? 0.0f : (SC(kw, kw) + SC(k, kw - 1));
          else if (g < w - 1 && k >= 1) v0 = si[kw][k + g + 1] + pf_ssg[t] + pf_sib[t];
          if (w > 64) {
            int j = g + 64;
            if (j == w - 1) v1 = (k == 0) ? 0.0f : (SC(kw, kw) + SC(k, kw - 1));
            else if (j < w - 1 && k >= 1) v1 = si[kw][k + j + 1] + pf_ssg[12 + t] + pf_sib[12 + t];
          }
          float r = wave_lse2(v0, v1);
          if (g == 0) si[kw][k] = r + arc_b[k * S + kw];
        } else {
          // S(k, kw) = lse_j C(k->k+j) + C(kw->k+j+1)
          if (g < w) v0 = SC(k, k + g) + SC(kw, k + g + 1);
          if (w > 64) {
            int j = g + 64;
            if (j < w) v1 = SC(k, k + j) + SC(kw, k + j + 1);
          }
          float r = wave_lse2(v0, v1);
          if (g == 0) { ssg[k * S + kw] = r; ssg[kw * S + k] = r; }
        }
      }
    }
    __syncthreads();

    // ---- prefetch sib/ssg for width w+1 (consumed next phase 1); latency
    //      hides under phase 2 + barrier. Guards mirror the consume exactly.
    const int wn = w + 1;
    if (wn < S) {
      const int nk2 = S - wn;
      const int T12 = 3 * nk2;
#pragma unroll
      for (int t = 0; t < MAXT; ++t) {
        const int task = wid + 16 * t;
        if (task < T12) {
          const int type = (task < nk2) ? 0 : ((task < 2 * nk2) ? 1 : 2);
          const int k = task - type * nk2;
          const int kw = k + wn;
          if (type == 0 && k >= 1) {
            if (g >= 1 && g < wn) {
              pf_sib[t] = SBraw[(size_t)(kw * S + k) * S + k + g];
              pf_ssg[t] = ssg[kw * S + k + g];
            }
            if (wn > 64) {
              int j = g + 64;
              if (j < wn) {
                pf_sib[12 + t] = SBraw[(size_t)(kw * S + k) * S + k + j];
                pf_ssg[12 + t] = ssg[kw * S + k + j];
              }
            }
          } else if (type == 1 && k >= 1) {
            if (g < wn - 1) {
              pf_sib[t] = SBraw[(size_t)(k * S + kw) * S + k + g + 1];
              pf_ssg[t] = ssg[k * S + k + g + 1];
            }
            if (wn > 64) {
              int j = g + 64;
              if (j < wn - 1) {
                pf_sib[12 + t] = SBraw[(size_t)(k * S + kw) * S + k + j + 1];
                pf_ssg[12 + t] = ssg[k * S + k + j + 1];
              }
            }
          }
        }
      }
    }

    // ---- phase 2: type0=cl, type1=cr (LDS-only; dynamic loop) ----
    const int T2 = 2 * nk;
    for (int task = wid; task < T2; task += 16) {
      const int type = (task < nk) ? 0 : 1;
      const int k = task - type * nk;
      const int kw = k + w;
      float v0 = NEGF, v1 = NEGF;
      if (type == 0) {
        // C(kw -> k) = lse_j C(k+j -> k) + I(kw -> k+j)   [sc column read]
        if (g < w) v0 = SC(k + g, k) + si[kw][k + g];
        if (w > 64) { int j = g + 64; if (j < w) v1 = SC(k + j, k) + si[kw][k + j]; }
        float r = wave_lse2(v0, v1);
        if (g == 0) SC(kw, k) = r;
      } else {
        // C(k -> kw) = lse_j I(k -> k+j+1) + C(k+j+1 -> kw)
        if (g < w) v0 = si[k][k + g + 1] + SC(k + g + 1, kw);
        if (w > 64) { int j = g + 64; if (j < w) v1 = si[k][k + j + 1] + SC(k + j + 1, kw); }
        float r = wave_lse2(v0, v1);
        if (g == 0) {
          if (k == 0) {
            // single-root kill: C(0->w) survives only at w == len
            if (w == len) { g_logZ[b] = r; SC(0, w) = r; }
            else SC(0, w) = NEGF;
          } else {
            SC(k, kw) = r;
          }
        }
      }
    }
    __syncthreads();
  }
}

// Gather score: masked arc scores + positive-sibling scores, count mask.
__global__ __launch_bounds__(256) void score_kernel(
    const float* __restrict__ arc, const float* __restrict__ sib,
    const unsigned char* __restrict__ mask, const int* __restrict__ arcs,
    const int* __restrict__ sibs, int B)
{
  __shared__ bool bytes_sh;
  if (threadIdx.x == 0) {
    int c = 0;
    for (int i = 0; i < S; ++i) c += (mask[i] != 0);
    bytes_sh = (c >= 64);
  }
  __syncthreads();
  const bool bytes = bytes_sh;

  const int total = B * S * S;
  int tid = blockIdx.x * blockDim.x + threadIdx.x;
  float sum = 0.f, cnt = 0.f;
  for (int e = tid; e < total; e += gridDim.x * blockDim.x) {
    int sv = sibs[e];
    if (sv > 0) sum += sib[(size_t)e * S + sv];
    if ((e & (S - 1)) == 0) {           // once per (b,i)
      int bi = e >> 7;
      if (mask_at(mask, bi, bytes)) { sum += arc[(size_t)bi * S + arcs[bi]]; cnt += 1.f; }
    }
  }
  __shared__ float rs[256], rc[256];
  rs[threadIdx.x] = sum; rc[threadIdx.x] = cnt;
  __syncthreads();
  for (int off = 128; off; off >>= 1) {
    if (threadIdx.x < off) {
      rs[threadIdx.x] += rs[threadIdx.x + off];
      rc[threadIdx.x] += rc[threadIdx.x + off];
    }
    __syncthreads();
  }
  if (threadIdx.x == 0) {
    g_partials[blockIdx.x * 2]     = rs[0];
    g_partials[blockIdx.x * 2 + 1] = rc[0];
  }
}

__global__ __launch_bounds__(256) void final_kernel(int B, float* __restrict__ out)
{
  __shared__ float rs[256], rc[256];
  int t = threadIdx.x;
  float v = -g_partials[t * 2];
  float c = g_partials[t * 2 + 1];
  if (t < B) v += g_logZ[t];
  rs[t] = v; rc[t] = c;
  __syncthreads();
  for (int off = 128; off; off >>= 1) {
    if (t < off) { rs[t] += rs[t + off]; rc[t] += rc[t + off]; }
    __syncthreads();
  }
  if (t == 0) out[0] = rs[0] / rc[0];   // (logZ - score) / mask.sum()
}

extern "C" void kernel_launch(void* const* d_in, const int* in_sizes, int n_in,
                              void* d_out, int out_size, void* d_ws, size_t ws_size,
                              hipStream_t stream) {
  const float* s_arc = (const float*)d_in[0];
  const float* s_sib = (const float*)d_in[1];
  const unsigned char* mask = (const unsigned char*)d_in[2];
  const int* arcs = (const int*)d_in[3];
  const int* sibs = (const int*)d_in[4];
  int B = in_sizes[0] / (S * S);
  if (B > MAXB) B = MAXB;

  score_kernel<<<dim3(256), dim3(256), 0, stream>>>(s_arc, s_sib, mask, arcs, sibs, B);
  dp_kernel<<<dim3(B), dim3(1024), 0, stream>>>(s_arc, s_sib, mask);
  final_kernel<<<dim3(1), dim3(256), 0, stream>>>(B, (float*)d_out);
}

// Round 5
// 1944.023 us; speedup vs baseline: 1.4612x; 1.3012x over previous
//
#include <hip/hip_runtime.h>

#define S 128
#define NEGF (-1e30f)
#define MAXB 16
#define PF_LO 18   // max phase-1 passes: ceil(3*95/16) at w=33
#define PF_HI 12   // max phase-1 passes when w>64: ceil(3*63/16)

// Static device workspace (d_ws proved unreliable in rounds 0-2).
__device__ float g_ssg[MAXB * S * S];   // sibling spans, both orientations
__device__ float g_logZ[MAXB];
__device__ float g_partials[512];

// sc is read both row-wise and column-wise: XOR-swizzle the column index.
#define SC(r, c) sc[r][(c) ^ ((r) & 31)]

__device__ __forceinline__ bool mask_at(const unsigned char* mask, int idx, bool bytes) {
  return bytes ? (mask[idx] != 0) : (((const int*)mask)[idx] != 0);
}

// ---- cross-lane primitives (DPP = pure VALU; no LDS path) ----
template <int CTRL>
__device__ __forceinline__ float dpp_f(float x) {
  int i = __float_as_int(x);
  return __int_as_float(__builtin_amdgcn_update_dpp(i, i, CTRL, 0xF, 0xF, false));
}
__device__ __forceinline__ float swz16_f(float x) {  // xor16 butterfly within 32
  return __int_as_float(__builtin_amdgcn_ds_swizzle(__float_as_int(x), 0x401F));
}
__device__ __forceinline__ float rdl63_f(float x) {
  return __int_as_float(__builtin_amdgcn_readlane(__float_as_int(x), 63));
}

// Group logsumexp over lanes of a G=2^lgG group (uniform lgG per width).
// Candidates: v0 (lane jg) and, when dual, v1 (lane jg+64 slot). Levels:
//  xor1: quad_perm[1,0,3,2]=0xB1   xor2: quad_perm[2,3,0,1]=0x4E
//  xor4: row_half_mirror=0x141 (quads uniform)  xor8: row_mirror=0x140
//  G=32: + ds_swizzle xor16 (butterfly, both 32-groups)
//  G=64: + row_bcast15=0x142 / row_bcast31=0x143 reduce into lane 63,
//        then readlane -> SGPR-uniform (valid: one group per wave).
__device__ __forceinline__ float lse_grp(float v0, float v1, int lgG, bool dual) {
  float m = dual ? fmaxf(v0, v1) : v0;
  if (lgG > 0) m = fmaxf(m, dpp_f<0xB1>(m));
  if (lgG > 1) m = fmaxf(m, dpp_f<0x4E>(m));
  if (lgG > 2) m = fmaxf(m, dpp_f<0x141>(m));
  if (lgG > 3) m = fmaxf(m, dpp_f<0x140>(m));
  if (lgG == 5) m = fmaxf(m, swz16_f(m));
  if (lgG == 6) {
    m = fmaxf(m, dpp_f<0x142>(m));
    m = fmaxf(m, dpp_f<0x143>(m));
    m = rdl63_f(m);
  }
  float s = __expf(v0 - m);
  if (dual) s += __expf(v1 - m);
  if (lgG > 0) s += dpp_f<0xB1>(s);
  if (lgG > 1) s += dpp_f<0x4E>(s);
  if (lgG > 2) s += dpp_f<0x141>(s);
  if (lgG > 3) s += dpp_f<0x140>(s);
  if (lgG == 5) s += swz16_f(s);
  if (lgG == 6) {
    s += dpp_f<0x142>(s);   // lanes 0-15/32-47 double themselves: harmless,
    s += dpp_f<0x143>(s);   // lane 63 accumulates the true full sum
    s = rdl63_f(s);
  }
  return __logf(s) + m;
}

// One block (16 waves) per batch element. Semantics identical to round 4
// (verified absmax 0.0); only the task->lane mapping and reduction changed.
__global__ __launch_bounds__(1024) void dp_kernel(
    const float* __restrict__ arc,          // [B,S,S] s_arc[b,dep,head]
    const float* __restrict__ sib,          // [B,S,S,S] s_sib[b,dep,head,sib]
    const unsigned char* __restrict__ mask) // [B,S]
{
  __shared__ float si[S][S];
  __shared__ float sc[S][S];
  __shared__ int len_sh, cnt0_sh;

  const int b = blockIdx.x;
  const int tid = threadIdx.x;
  const float* arc_b = arc + (size_t)b * S * S;      // arc_b[dep*S+head]
  const float* SBraw = sib + (size_t)b * S * S * S;  // SBraw[dep][head][sib]
  float* ssg = g_ssg + (size_t)b * S * S;

  if (tid == 0) { len_sh = 0; cnt0_sh = 0; }
  __syncthreads();
  if (tid < S && mask[tid] != 0) atomicAdd(&cnt0_sh, 1);  // byte-interp of row 0
  for (int i = tid; i < S * S; i += 1024) {
    (&si[0][0])[i] = NEGF;
    (&sc[0][0])[i] = NEGF;
  }
  __syncthreads();
  const bool bytes = (cnt0_sh >= 64);
  if (tid < S) {
    SC(tid, tid) = 0.0f;
    if (mask_at(mask, b * S + tid, bytes)) atomicAdd(&len_sh, 1);
  }
  __syncthreads();
  const int len = min(len_sh, S - 1);
  if (tid == 0) g_logZ[b] = 0.0f;

  float pf[PF_LO], pf_hi[PF_HI];   // sib prefetch (statically indexed)

  for (int w = 1; w < S; ++w) {
    const int nk = S - w;
    const int lgG = (w <= 1) ? 0 : min(6, 32 - __clz(w - 1));
    const int G = 1 << lgG;
    const int NG = 1024 >> lgG;       // parallel groups in block
    const int gid = tid >> lgG;
    const int jg = tid & (G - 1);
    const bool dual = (w > 64);
    const int T1 = 3 * nk;
    const int P1 = (T1 + NG - 1) >> (10 - lgG);

    // ---- phase 1: type0=ir, type1=il, type2=slr ----
#pragma unroll
    for (int t = 0; t < PF_LO; ++t) {
      if (t < P1) {
        const int task = gid + NG * t;
        const bool act = task < T1;
        int typ = 2, k = 0, kw = 0;
        if (act) {
          typ = (task < nk) ? 0 : ((task < 2 * nk) ? 1 : 2);
          k = task - typ * nk;
          kw = k + w;
        }
        // early global loads (ssg L2 + arc L2), hidden under the reduce
        float ssgv = 0.f, ssgh = 0.f, arcv = 0.f;
        if (act) {
          if (typ == 0) {
            if (jg >= 1 && jg < w && k >= 1) ssgv = ssg[kw * S + k + jg];
            if (dual && k >= 1) { int j = jg + 64; if (j < w) ssgh = ssg[kw * S + k + j]; }
            if (jg == 0) arcv = arc_b[kw * S + k];
          } else if (typ == 1) {
            if (jg < w - 1 && k >= 1) ssgv = ssg[k * S + k + jg + 1];
            if (dual && k >= 1) { int j = jg + 64; if (j < w - 1) ssgh = ssg[k * S + k + j + 1]; }
            if (jg == 0) arcv = arc_b[k * S + kw];
          }
        }
        float v0 = NEGF, v1 = NEGF;
        if (act) {
          if (typ == 0) {
            // I(k -> kw): j=0 base; j in [1,w) siblings (k>=1)
            if (jg == 0) v0 = SC(k, k) + SC(kw, k + 1);
            else if (jg < w && k >= 1) v0 = si[k][k + jg] + ssgv + pf[t];
            if (dual && k >= 1) { int j = jg + 64; if (j < w) v1 = si[k][k + j] + ssgh + pf_hi[t]; }
          } else if (typ == 1) {
            // I(kw -> k): j=w-1 base; j in [0,w-1) siblings (k>=1)
            if (jg == w - 1) v0 = (k == 0) ? 0.0f : (SC(kw, kw) + SC(k, kw - 1));
            else if (jg < w - 1 && k >= 1) v0 = si[kw][k + jg + 1] + ssgv + pf[t];
            if (dual) {
              int j = jg + 64;
              if (j == w - 1) v1 = (k == 0) ? 0.0f : (SC(kw, kw) + SC(k, kw - 1));
              else if (j < w - 1 && k >= 1) v1 = si[kw][k + j + 1] + ssgh + pf_hi[t];
            }
          } else {
            // S(k, kw) = lse_j C(k->k+j) + C(kw->k+j+1)
            if (jg < w) v0 = SC(k, k + jg) + SC(kw, k + jg + 1);
            if (dual) { int j = jg + 64; if (j < w) v1 = SC(k, k + j) + SC(kw, k + j + 1); }
          }
        }
        float r = lse_grp(v0, v1, lgG, dual);
        if (act && jg == 0) {
          if (typ == 0) si[k][kw] = r + arcv;
          else if (typ == 1) si[kw][k] = r + arcv;
          else { ssg[k * S + kw] = r; ssg[kw * S + k] = r; }
        }
      }
    }
    __syncthreads();

    // ---- prefetch sib (HBM) for width w+1; guards mirror the consume ----
    const int wn = w + 1;
    if (wn < S) {
      const int nk2 = S - wn;
      const int lgn = min(6, 32 - __clz(wn - 1));   // wn >= 2
      const int NGn = 1024 >> lgn;
      const int gidn = tid >> lgn;
      const int jn = tid & ((1 << lgn) - 1);
      const bool dn = (wn > 64);
      const int T12 = 3 * nk2;
      const int P1n = (T12 + NGn - 1) >> (10 - lgn);
#pragma unroll
      for (int t = 0; t < PF_LO; ++t) {
        if (t < P1n) {
          const int task = gidn + NGn * t;
          if (task < T12) {
            const int typ = (task < nk2) ? 0 : ((task < 2 * nk2) ? 1 : 2);
            const int k = task - typ * nk2;
            const int kw = k + wn;
            if (typ == 0 && k >= 1) {
              if (jn >= 1 && jn < wn) pf[t] = SBraw[(size_t)(kw * S + k) * S + k + jn];
              if (dn && t < PF_HI) { int j = jn + 64; if (j < wn) pf_hi[t] = SBraw[(size_t)(kw * S + k) * S + k + j]; }
            } else if (typ == 1 && k >= 1) {
              if (jn < wn - 1) pf[t] = SBraw[(size_t)(k * S + kw) * S + k + jn + 1];
              if (dn && t < PF_HI) { int j = jn + 64; if (j < wn - 1) pf_hi[t] = SBraw[(size_t)(k * S + kw) * S + k + j + 1]; }
            }
          }
        }
      }
    }

    // ---- phase 2: type0=cl, type1=cr (LDS-only) ----
    const int T2 = 2 * nk;
    const int P2 = (T2 + NG - 1) >> (10 - lgG);
#pragma unroll
    for (int t = 0; t < PF_HI; ++t) {   // max ceil(2*95/16)=12
      if (t < P2) {
        const int task = gid + NG * t;
        const bool act = task < T2;
        int typ = 0, k = 0, kw = 0;
        if (act) {
          typ = (task < nk) ? 0 : 1;
          k = task - typ * nk;
          kw = k + w;
        }
        float v0 = NEGF, v1 = NEGF;
        if (act) {
          if (typ == 0) {
            // C(kw -> k) = lse_j C(k+j -> k) + I(kw -> k+j)  [sc column read]
            if (jg < w) v0 = SC(k + jg, k) + si[kw][k + jg];
            if (dual) { int j = jg + 64; if (j < w) v1 = SC(k + j, k) + si[kw][k + j]; }
          } else {
            // C(k -> kw) = lse_j I(k -> k+j+1) + C(k+j+1 -> kw)
            if (jg < w) v0 = si[k][k + jg + 1] + SC(k + jg + 1, kw);
            if (dual) { int j = jg + 64; if (j < w) v1 = si[k][k + j + 1] + SC(k + j + 1, kw); }
          }
        }
        float r = lse_grp(v0, v1, lgG, dual);
        if (act && jg == 0) {
          if (typ == 0) SC(kw, k) = r;
          else if (k == 0) {
            // single-root kill: C(0->w) survives only at w == len
            if (w == len) { g_logZ[b] = r; SC(0, w) = r; }
            else SC(0, w) = NEGF;
          } else {
            SC(k, kw) = r;
          }
        }
      }
    }
    __syncthreads();
  }
}

// Gather score: masked arc scores + positive-sibling scores, count mask.
__global__ __launch_bounds__(256) void score_kernel(
    const float* __restrict__ arc, const float* __restrict__ sib,
    const unsigned char* __restrict__ mask, const int* __restrict__ arcs,
    const int* __restrict__ sibs, int B)
{
  __shared__ bool bytes_sh;
  if (threadIdx.x == 0) {
    int c = 0;
    for (int i = 0; i < S; ++i) c += (mask[i] != 0);
    bytes_sh = (c >= 64);
  }
  __syncthreads();
  const bool bytes = bytes_sh;

  const int total = B * S * S;
  int tid = blockIdx.x * blockDim.x + threadIdx.x;
  float sum = 0.f, cnt = 0.f;
  for (int e = tid; e < total; e += gridDim.x * blockDim.x) {
    int sv = sibs[e];
    if (sv > 0) sum += sib[(size_t)e * S + sv];
    if ((e & (S - 1)) == 0) {
      int bi = e >> 7;
      if (mask_at(mask, bi, bytes)) { sum += arc[(size_t)bi * S + arcs[bi]]; cnt += 1.f; }
    }
  }
  __shared__ float rs[256], rc[256];
  rs[threadIdx.x] = sum; rc[threadIdx.x] = cnt;
  __syncthreads();
  for (int off = 128; off; off >>= 1) {
    if (threadIdx.x < off) {
      rs[threadIdx.x] += rs[threadIdx.x + off];
      rc[threadIdx.x] += rc[threadIdx.x + off];
    }
    __syncthreads();
  }
  if (threadIdx.x == 0) {
    g_partials[blockIdx.x * 2]     = rs[0];
    g_partials[blockIdx.x * 2 + 1] = rc[0];
  }
}

__global__ __launch_bounds__(256) void final_kernel(int B, float* __restrict__ out)
{
  __shared__ float rs[256], rc[256];
  int t = threadIdx.x;
  float v = -g_partials[t * 2];
  float c = g_partials[t * 2 + 1];
  if (t < B) v += g_logZ[t];
  rs[t] = v; rc[t] = c;
  __syncthreads();
  for (int off = 128; off; off >>= 1) {
    if (t < off) { rs[t] += rs[t + off]; rc[t] += rc[t + off]; }
    __syncthreads();
  }
  if (t == 0) out[0] = rs[0] / rc[0];
}

extern "C" void kernel_launch(void* const* d_in, const int* in_sizes, int n_in,
                              void* d_out, int out_size, void* d_ws, size_t ws_size,
                              hipStream_t stream) {
  const float* s_arc = (const float*)d_in[0];
  const float* s_sib = (const float*)d_in[1];
  const unsigned char* mask = (const unsigned char*)d_in[2];
  const int* arcs = (const int*)d_in[3];
  const int* sibs = (const int*)d_in[4];
  int B = in_sizes[0] / (S * S);
  if (B > MAXB) B = MAXB;

  score_kernel<<<dim3(256), dim3(256), 0, stream>>>(s_arc, s_sib, mask, arcs, sibs, B);
  dp_kernel<<<dim3(B), dim3(1024), 0, stream>>>(s_arc, s_sib, mask);
  final_kernel<<<dim3(1), dim3(256), 0, stream>>>(B, (float*)d_out);
}